// Round 13
// baseline (364.642 us; speedup 1.0000x reference)
//
#include <hip/hip_runtime.h>

typedef _Float16 f16;
typedef _Float16 f16x8 __attribute__((ext_vector_type(8)));
typedef float f32x4 __attribute__((ext_vector_type(4)));

#define LN4 1.3862943611198906f

__device__ __forceinline__ void gl_lds16(const void* g, void* l) {
    typedef unsigned int u32;
    __builtin_amdgcn_global_load_lds(
        (const __attribute__((address_space(1))) u32*)(g),
        (__attribute__((address_space(3))) u32*)(l), 16, 0, 0);
}

// ===========================================================================
// Weight prep: fp32 W[27][CIN][CIN] -> f16 hi/lo transposed:
// WT[d][tap][ h(CIN) | l(CIN) ], d<CIN, tap<28 (tap 27 = zeros).
// ===========================================================================
template<int CIN>
__global__ __launch_bounds__(256) void prep_wt(
    const float* __restrict__ W, f16* __restrict__ dst)
{
    const int RE = 2 * CIN;
    int total = CIN * 28 * CIN;
    for (int i = blockIdx.x * 256 + threadIdx.x; i < total; i += gridDim.x * 256) {
        int d = i / (28 * CIN);
        int rem = i - d * (28 * CIN);
        int tap = rem / CIN;
        int c = rem - tap * CIN;
        float v = (tap < 27) ? W[(size_t)(tap * CIN + c) * CIN + d] : 0.f;
        f16 h = (f16)v;
        size_t base = (size_t)d * (28 * RE) + (size_t)tap * RE;
        dst[base + c] = h;
        dst[base + CIN + c] = (f16)(v - (float)h);
    }
}

// ===========================================================================
// B-fragment table for the fused P-projection (R11-verified layout):
// FG[((pass*KB+kb)*4+ct)][lane][8] f16.
// ===========================================================================
template<int CIN>
__global__ __launch_bounds__(256) void prep_gfrag(
    const float* __restrict__ Ws, f16* __restrict__ FG)
{
    constexpr int KB = (2 * CIN) / 32;
    int total = 2 * KB * 4 * 512;
    for (int i = blockIdx.x * 256 + threadIdx.x; i < total; i += gridDim.x * 256) {
        int j = i & 7;
        int lane = (i >> 3) & 63;
        int blk = i >> 9;
        int ct = blk & 3;
        int kbp = blk >> 2;
        int kb = kbp % KB;
        int pass = kbp / KB;
        int k = kb * 32 + ((lane >> 4) << 3) + j;
        int col = ct * 16 + (lane & 15);
        int c = (k < CIN) ? k : k - CIN;
        float w = 0.f;
        if (col < 54) {
            int t = col >> 1, jj = col & 1;
            w = Ws[((size_t)t * CIN + c) * 2 + jj];
        }
        f16 wh = (f16)w;
        FG[i] = (pass == 0) ? wh : ((k < CIN) ? (f16)(w - (float)wh) : (f16)0.f);
    }
}

// ===========================================================================
// Feature split (+optional gating): rows [h(CIN)|l(CIN)] f16, zero row at N.
// ===========================================================================
template<int CIN>
__global__ __launch_bounds__(256) void split_gated(
    const float* __restrict__ f, const float* __restrict__ mask,
    const int* __restrict__ parent, f16* __restrict__ Fc, int N)
{
    int i = blockIdx.x * 256 + threadIdx.x;
    if (i >= (N + 1) * CIN) return;
    int n = i / CIN, c = i - n * CIN;
    float v = 0.f;
    if (n < N) {
        bool a = parent ? (mask[parent[n]] != 0.f) : true;
        v = a ? f[i] : 0.f;
    }
    f16 h = (f16)v;
    Fc[(size_t)n * (2 * CIN) + c] = h;
    Fc[(size_t)n * (2 * CIN) + CIN + c] = (f16)(v - (float)h);
}

// fused act-gate + neighbor-flag expand (level 3)
__global__ __launch_bounds__(256) void gate_expand(
    const float* __restrict__ mask, const int* __restrict__ parent,
    const int* __restrict__ nbr, float* __restrict__ act,
    int* __restrict__ flag, int N)
{
    int m = blockIdx.x * 256 + threadIdx.x;
    if (m >= N) return;
    float a = mask[parent[m]];
    act[m] = a;
    if (a == 0.f) return;
    #pragma unroll 1
    for (int t = 0; t < 27; ++t) {
        int idx = nbr[(size_t)m * 27 + t];
        if (idx < N) flag[idx] = 1;
    }
}

// flag[nbr[m][t]] = 1 for every flagged source m (int src).
__global__ __launch_bounds__(256) void expand_kernel(
    const int* __restrict__ src, const int* __restrict__ nbr,
    int* __restrict__ flag, int N)
{
    int m = blockIdx.x * 256 + threadIdx.x;
    if (m >= N) return;
    if (src[m] == 0) return;
    #pragma unroll 1
    for (int t = 0; t < 27; ++t) {
        int idx = nbr[(size_t)m * 27 + t];
        if (idx < N) flag[idx] = 1;
    }
}

// wave-aggregated compaction: list[0..cnt) = rows with flag!=0
__global__ __launch_bounds__(256) void compact_kernel(
    const int* __restrict__ flag, int* __restrict__ list,
    int* __restrict__ cnt, int N)
{
    int i = blockIdx.x * 256 + threadIdx.x;
    int lane = threadIdx.x & 63;
    bool f = (i < N) && (flag[i] != 0);
    unsigned long long m = __ballot(f);
    int base = 0;
    if (lane == 0 && m) base = atomicAdd(cnt, __popcll(m));
    base = __shfl(base, 0);
    if (f) list[base + __popcll(m & ((1ull << lane) - 1ull))] = i;
}

// ===========================================================================
// Dense MFMA conv tile CIN->CIN (f16 hi/lo split, 3-term), 64 rows/block,
// 2 taps/phase, 14 phases — R10/R13-measured main loop + R15-measured fused
// P-projection epilogue. R18: staging source pointers hoisted out of the
// phase loop (computed once, advanced by constant STEP/phase) — removes the
// per-phase div/mod/xor address chain that dominated VALUBusy. Numerically
// identical addressing (verified in R12's probe); pointer array is
// compile-time-indexed (rule-#20-safe), ~10 extra VGPRs at KB=3.
// ===========================================================================
template<int CIN>
__global__ __launch_bounds__(256, 3) void conv_tile(
    const f16* __restrict__ F, const int* __restrict__ nbr,
    const f16* __restrict__ WT, const f16* __restrict__ FG,
    float* __restrict__ P, int N, int nTiles)
{
    constexpr int RE = 2 * CIN;        // f16 per row (hi|lo)
    constexpr int KB = RE / 32;        // K chunks per phase
    constexpr int CT = CIN / 16;       // acc tiles over output cols
    constexpr int CPT = RE / 8;        // 16B chunks per tap row in BS
    constexpr int CPR = 2 * CPT;       // chunks per BS row (2 taps)
    constexpr int PB = CPR * 16;       // BS row bytes
    constexpr int LRE = RE + 8;        // padded LDS row (f16) for epilogue
    constexpr int NCH = CIN * CPR;     // staged 16B chunks per phase
    constexpr int NIT = (NCH + 255) / 256;
    constexpr int STEP = 2 * RE * 2;   // staging src advance per phase (bytes)
    __shared__ __align__(16) char BS[CIN * PB];

    const int t = threadIdx.x;
    const int lane = t & 63;
    const int l16 = lane & 15;
    const int quad = lane >> 4;
    const int wv = t >> 6;

    int q8 = (nTiles + 7) >> 3;
    int tile = (blockIdx.x & 7) * q8 + (blockIdx.x >> 3);
    if (tile >= nTiles) return;
    const int m0 = tile * 64;
    const int grow = m0 + wv * 16 + l16;

    f16x8 ahA[KB], alA[KB], ahB[KB], alB[KB];

    auto loadA = [&](int p, f16x8 (&ah)[KB], f16x8 (&al)[KB]) {
        int i0 = N, i1 = N;
        if (grow < N) {
            i0 = nbr[(size_t)grow * 27 + 2 * p];
            if (2 * p + 1 < 27) i1 = nbr[(size_t)grow * 27 + 2 * p + 1];
        }
        #pragma unroll
        for (int kb = 0; kb < KB; ++kb) {
            int ko = kb * 32 + quad * 8;
            int ts = ko >= CIN;
            int c2 = ko - (ts ? CIN : 0);
            const f16* ap = F + (size_t)(ts ? i1 : i0) * RE + c2;
            ah[kb] = *(const f16x8*)ap;
            al[kb] = *(const f16x8*)(ap + CIN);
        }
    };

    // hoisted staging source pointers (phase 0); advance by STEP per phase
    const char* ssrc[NIT];
    #pragma unroll
    for (int it = 0; it < NIT; ++it) {
        int i = t + it * 256;
        int iv = (i < NCH) ? i : 0;
        int d = iv / CPR, cs = iv - d * CPR;
        int c = (cs & ~7) | ((cs ^ d) & 7);
        int tp = c / CPT, cc = c - tp * CPT;
        ssrc[it] = (const char*)WT + (((size_t)d * 28 + tp) * RE + cc * 8) * 2;
    }

    auto stageB = [&]() {
        #pragma unroll
        for (int it = 0; it < NIT; ++it) {
            int i = t + it * 256;
            if (i < NCH) gl_lds16(ssrc[it], BS + (size_t)i * 16);
            ssrc[it] += STEP;
        }
    };

    f32x4 acc[CT];
    #pragma unroll
    for (int ct = 0; ct < CT; ++ct) acc[ct] = (f32x4){0.f, 0.f, 0.f, 0.f};

    auto compute = [&](f16x8 (&ah)[KB], f16x8 (&al)[KB]) {
        #pragma unroll
        for (int kb = 0; kb < KB; ++kb) {
            int ko = kb * 32 + quad * 8;
            int ts = ko >= CIN;
            int c2 = ko - (ts ? CIN : 0);
            int ch = ts * CPT + c2 / 8;
            int chl = ch + CIN / 8;
            #pragma unroll
            for (int ct = 0; ct < CT; ++ct) {
                int drow = ct * 16 + l16;
                int sb = (ch & ~7) | ((ch ^ drow) & 7);
                int sbl = (chl & ~7) | ((chl ^ drow) & 7);
                f16x8 bh = *(const f16x8*)(BS + drow * PB + sb * 16);
                f16x8 bl = *(const f16x8*)(BS + drow * PB + sbl * 16);
                acc[ct] = __builtin_amdgcn_mfma_f32_16x16x32_f16(ah[kb], bh, acc[ct], 0, 0, 0);
                acc[ct] = __builtin_amdgcn_mfma_f32_16x16x32_f16(al[kb], bh, acc[ct], 0, 0, 0);
                acc[ct] = __builtin_amdgcn_mfma_f32_16x16x32_f16(ah[kb], bl, acc[ct], 0, 0, 0);
            }
        }
    };

    loadA(0, ahA, alA);
    #pragma unroll 1
    for (int p = 0; p < 14; p += 2) {
        __syncthreads();
        stageB();
        loadA(p + 1, ahB, alB);          // p+1 <= 13 always
        __syncthreads();
        compute(ahA, alA);

        __syncthreads();
        stageB();
        if (p + 2 < 14) loadA(p + 2, ahA, alA);
        __syncthreads();
        compute(ahB, alB);
    }

    // ---- fused P-projection epilogue (R15-verified) ----
    __syncthreads();                       // BS free for reuse (all waves done)
    f16* LW = (f16*)BS + (size_t)wv * 16 * LRE;   // wave-private 16-row region

    // dump acc rows as the SAME hi/lo f16 split the old Y buffer used
    #pragma unroll
    for (int ct = 0; ct < CT; ++ct) {
        #pragma unroll
        for (int r = 0; r < 4; ++r) {
            int wrow = quad * 4 + r;
            int d = ct * 16 + l16;
            float v = acc[ct][r];
            f16 h = (f16)v;
            LW[wrow * LRE + d] = h;
            LW[wrow * LRE + CIN + d] = (f16)(v - (float)h);
        }
    }
    // wave-local RAW: same wave reads its own region (lgkmcnt ordering)

    f32x4 pa[4];
    #pragma unroll
    for (int ct = 0; ct < 4; ++ct) pa[ct] = (f32x4){0.f, 0.f, 0.f, 0.f};

    #pragma unroll
    for (int kb = 0; kb < KB; ++kb) {
        f16x8 a = *(const f16x8*)(LW + l16 * LRE + kb * 32 + quad * 8);
        #pragma unroll
        for (int ct = 0; ct < 4; ++ct) {
            f16x8 b = *(const f16x8*)(FG + ((size_t)((0 * KB + kb) * 4 + ct)) * 512 + lane * 8);
            pa[ct] = __builtin_amdgcn_mfma_f32_16x16x32_f16(a, b, pa[ct], 0, 0, 0);
        }
        #pragma unroll
        for (int ct = 0; ct < 4; ++ct) {
            f16x8 b = *(const f16x8*)(FG + ((size_t)((1 * KB + kb) * 4 + ct)) * 512 + lane * 8);
            pa[ct] = __builtin_amdgcn_mfma_f32_16x16x32_f16(a, b, pa[ct], 0, 0, 0);
        }
    }

    #pragma unroll
    for (int ct = 0; ct < 4; ++ct) {
        int col = ct * 16 + l16;
        if (col < 54) {
            #pragma unroll
            for (int r = 0; r < 4; ++r) {
                int row = m0 + wv * 16 + quad * 4 + r;
                if (row < N) P[(size_t)row * 54 + col] = pa[ct][r];
            }
        }
    }
}

// ===========================================================================
// Fused score-gather + ppn finalize (R11-verified).
// ===========================================================================
__global__ __launch_bounds__(256) void finalize_gather(
    const int* __restrict__ coords, const float* __restrict__ P,
    const int* __restrict__ nbr, float* __restrict__ ppn,
    float* __restrict__ mask, int N)
{
    int n = blockIdx.x * 256 + threadIdx.x;
    if (n >= N) return;
    float s0 = 0.f, s1 = 0.f;
    #pragma unroll
    for (int t = 0; t < 27; ++t) {
        int idx = nbr[(size_t)n * 27 + t];
        if (idx < N) {
            float2 v = *(const float2*)(P + (size_t)idx * 54 + 2 * t);
            s0 += v.x; s1 += v.y;
        }
    }
    ppn[(size_t)n * 6 + 0] = (float)coords[(size_t)n * 4 + 0];
    ppn[(size_t)n * 6 + 1] = (float)coords[(size_t)n * 4 + 1];
    ppn[(size_t)n * 6 + 2] = (float)coords[(size_t)n * 4 + 2];
    ppn[(size_t)n * 6 + 3] = (float)coords[(size_t)n * 4 + 3];
    ppn[(size_t)n * 6 + 4] = s0;
    ppn[(size_t)n * 6 + 5] = s1;
    mask[n] = (s1 - s0 > LN4) ? 1.0f : 0.0f;
}

// ===========================================================================
// Level 3 compute kernels over compacted lists (Round-0 measured, unchanged).
// ===========================================================================
__global__ __launch_bounds__(256) void lvl3_z_compute(
    const float* __restrict__ feat3, const int* __restrict__ nbr3,
    const float* __restrict__ act, const float* __restrict__ W3,
    float* __restrict__ z, const int* __restrict__ list,
    const int* __restrict__ cnt, int N)
{
    const int lane = threadIdx.x & 63;
    const int wid0 = (blockIdx.x * 256 + threadIdx.x) >> 6;
    const int nw = (gridDim.x * 256) >> 6;
    const int count = *cnt;
    const int c = lane;

    for (int w = wid0; w < count; w += nw) {
        const int n = list[w];
        int ld = N;
        if (lane < 27) ld = nbr3[(size_t)n * 27 + lane];
        bool valid = (lane < 27) && (ld < N);
        float a = valid ? act[ld] : 0.f;
        unsigned long long m = __ballot(a != 0.f);

        float acc = 0.f;
        while (m) {
            int t = __ffsll(m) - 1; m &= m - 1;
            int idx = __shfl(ld, t);
            const float4* f4 = (const float4*)(feat3 + (size_t)idx * 16);
            const float* wgt = W3 + (size_t)t * 256;
            #pragma unroll
            for (int q = 0; q < 4; ++q) {
                float4 fv = f4[q];
                if (c < 16) {
                    acc += fv.x * wgt[(4 * q + 0) * 16 + c];
                    acc += fv.y * wgt[(4 * q + 1) * 16 + c];
                    acc += fv.z * wgt[(4 * q + 2) * 16 + c];
                    acc += fv.w * wgt[(4 * q + 3) * 16 + c];
                }
            }
        }
        if (lane < 16) z[(size_t)n * 16 + lane] = acc;
    }
}

__global__ __launch_bounds__(256) void lvl3_pts_compute(
    const float* __restrict__ z, const int* __restrict__ zflag,
    const int* __restrict__ nbr3,
    const float* __restrict__ Wp, const float* __restrict__ Ws,
    const float* __restrict__ Wt, float* __restrict__ points,
    const int* __restrict__ list, const int* __restrict__ cnt, int N)
{
    const int lane = threadIdx.x & 63;
    const int wid0 = (blockIdx.x * 256 + threadIdx.x) >> 6;
    const int nw = (gridDim.x * 256) >> 6;
    const int count = *cnt;
    const int c = lane;

    for (int w = wid0; w < count; w += nw) {
        const int n = list[w];
        int ld = N;
        if (lane < 27) ld = nbr3[(size_t)n * 27 + lane];
        bool valid = (lane < 27) && (ld < N);
        int zf = valid ? zflag[ld] : 0;
        unsigned long long m = __ballot(zf != 0);

        float acc = 0.f;
        while (m) {
            int t = __ffsll(m) - 1; m &= m - 1;
            int idx = __shfl(ld, t);
            const float4* z4 = (const float4*)(z + (size_t)idx * 16);
            #pragma unroll
            for (int q = 0; q < 4; ++q) {
                float4 zv = z4[q];
                if (c < 10) {
                    #pragma unroll
                    for (int j = 0; j < 4; ++j) {
                        int k = 4 * q + j;
                        int kc = t * 16 + k;
                        float wv = (c < 3) ? Wp[(size_t)kc * 3 + c]
                                 : (c < 5) ? Ws[(size_t)kc * 2 + (c - 3)]
                                           : Wt[(size_t)kc * 5 + (c - 5)];
                        float zj = (j == 0) ? zv.x : (j == 1) ? zv.y : (j == 2) ? zv.z : zv.w;
                        acc += zj * wv;
                    }
                }
            }
        }
        if (lane < 10) points[(size_t)n * 10 + lane] = acc;
    }
}

// ===========================================================================
extern "C" void kernel_launch(void* const* d_in, const int* in_sizes, int n_in,
                              void* d_out, int out_size, void* d_ws, size_t ws_size,
                              hipStream_t stream)
{
    const float* feat1 = (const float*)d_in[0];
    const float* feat2 = (const float*)d_in[1];
    const float* feat3 = (const float*)d_in[2];
    const float* W1    = (const float*)d_in[3];
    const float* W1s   = (const float*)d_in[4];
    const float* W2    = (const float*)d_in[5];
    const float* W2s   = (const float*)d_in[6];
    const float* W3    = (const float*)d_in[7];
    const float* W3p   = (const float*)d_in[8];
    const float* W3s   = (const float*)d_in[9];
    const float* W3t   = (const float*)d_in[10];
    const int* nbr1    = (const int*)d_in[11];
    const int* nbr2    = (const int*)d_in[12];
    const int* nbr3    = (const int*)d_in[13];
    const int* parent2 = (const int*)d_in[14];
    const int* parent3 = (const int*)d_in[15];
    const int* coords1 = (const int*)d_in[16];
    const int* coords2 = (const int*)d_in[17];

    const int N1 = in_sizes[0] / 80;
    const int N2 = in_sizes[1] / 48;
    const int N3 = in_sizes[2] / 16;

    float* out = (float*)d_out;
    float* o_points = out;                              // [N3,10]
    float* o_ppn1   = o_points + (size_t)N3 * 10;       // [N1,6]
    float* o_ppn2   = o_ppn1 + (size_t)N1 * 6;          // [N2,6]
    float* o_mask1  = o_ppn2 + (size_t)N2 * 6;          // [N1]
    float* o_mask2  = o_mask1 + (size_t)N1;             // [N2]

    char* wp = (char*)d_ws;
    auto alloc = [&](size_t bytes) -> char* {
        char* r = wp; wp += (bytes + 255) & ~(size_t)255; return r;
    };
    auto A256 = [](size_t b) { return (b + 255) & ~(size_t)255; };

    f16*   WT1 = (f16*)alloc((size_t)80 * 28 * 160 * 2);
    f16*   WT2 = (f16*)alloc((size_t)48 * 28 * 96 * 2);
    f16*   FG1 = (f16*)alloc((size_t)2 * 5 * 4 * 512 * 2);
    f16*   FG2 = (f16*)alloc((size_t)2 * 3 * 4 * 512 * 2);
    float* act3 = (float*)alloc((size_t)N3 * 4);
    int*   cnts = (int*)alloc(2 * 4);    // [cntz, cntp]

    // Fa: split features (levels 1,2 sequentially)
    size_t fa1 = (size_t)(N1 + 1) * 320, fa2 = (size_t)(N2 + 1) * 192;
    f16* Fa = (f16*)alloc(fa1 > fa2 ? fa1 : fa2);

    // P union: P projection (levels 1,2), then level-3 flags/lists/zbuf
    size_t pmax = (size_t)(N1 > N2 ? N1 : N2) * 216 + 256;
    size_t l3b = 4 * A256((size_t)N3 * 4) + A256((size_t)N3 * 16 * 4);
    size_t szP = pmax > l3b ? pmax : l3b;
    char* Pu = alloc(szP);
    float* P = (float*)Pu;
    char* q3 = Pu;
    int*   flagz = (int*)q3; q3 += A256((size_t)N3 * 4);
    int*   listz = (int*)q3; q3 += A256((size_t)N3 * 4);
    int*   flagp = (int*)q3; q3 += A256((size_t)N3 * 4);
    int*   listp = (int*)q3; q3 += A256((size_t)N3 * 4);
    float* zbuf  = (float*)q3;

    auto cdiv = [](long long a, long long b) { return (int)((a + b - 1) / b); };

    hipMemsetAsync(cnts, 0, 2 * 4, stream);
    hipMemsetAsync(o_points, 0, (size_t)N3 * 10 * 4, stream);

    // ---- weight prep ----
    prep_wt<80><<<700, 256, 0, stream>>>(W1, WT1);
    prep_wt<48><<<cdiv(48 * 28 * 48, 256), 256, 0, stream>>>(W2, WT2);
    prep_gfrag<80><<<80, 256, 0, stream>>>(W1s, FG1);
    prep_gfrag<48><<<48, 256, 0, stream>>>(W2s, FG2);

    // ---- level 1: fused conv+P-projection -> fused finalize ----
    {
        int Tc = cdiv(N1, 64);
        dim3 gc(8 * cdiv(Tc, 8));
        split_gated<80><<<cdiv((size_t)(N1 + 1) * 80, 256), 256, 0, stream>>>(
            feat1, nullptr, nullptr, Fa, N1);
        conv_tile<80><<<gc, 256, 0, stream>>>(Fa, nbr1, WT1, FG1, P, N1, Tc);
        finalize_gather<<<cdiv(N1, 256), 256, 0, stream>>>(
            coords1, P, nbr1, o_ppn1, o_mask1, N1);
    }

    // ---- level 2: fused conv+P-projection -> fused finalize ----
    {
        int Tc = cdiv(N2, 64);
        dim3 gc(8 * cdiv(Tc, 8));
        split_gated<48><<<cdiv((size_t)(N2 + 1) * 48, 256), 256, 0, stream>>>(
            feat2, o_mask1, parent2, Fa, N2);
        conv_tile<48><<<gc, 256, 0, stream>>>(Fa, nbr2, WT2, FG2, P, N2, Tc);
        finalize_gather<<<cdiv(N2, 256), 256, 0, stream>>>(
            coords2, P, nbr2, o_ppn2, o_mask2, N2);
    }

    // ---- level 3: fused gate+expand -> compact -> z -> expand -> compact -> pts
    // (zbuf memset removed: lvl3_pts only reads z rows with zflag!=0, all of
    //  which lvl3_z fully writes)
    hipMemsetAsync(flagz, 0, (size_t)N3 * 4, stream);
    hipMemsetAsync(flagp, 0, (size_t)N3 * 4, stream);
    gate_expand<<<cdiv(N3, 256), 256, 0, stream>>>(o_mask2, parent3, nbr3,
                                                   act3, flagz, N3);
    compact_kernel<<<cdiv(N3, 256), 256, 0, stream>>>(flagz, listz, &cnts[0], N3);
    lvl3_z_compute<<<2048, 256, 0, stream>>>(feat3, nbr3, act3, W3, zbuf,
                                             listz, &cnts[0], N3);
    expand_kernel<<<cdiv(N3, 256), 256, 0, stream>>>(flagz, nbr3, flagp, N3);
    compact_kernel<<<cdiv(N3, 256), 256, 0, stream>>>(flagp, listp, &cnts[1], N3);
    lvl3_pts_compute<<<2048, 256, 0, stream>>>(zbuf, flagz, nbr3, W3p, W3s, W3t,
                                               o_points, listp, &cnts[1], N3);
}

// Round 14
// 341.263 us; speedup vs baseline: 1.0685x; 1.0685x over previous
//
#include <hip/hip_runtime.h>

typedef _Float16 f16;
typedef _Float16 f16x8 __attribute__((ext_vector_type(8)));
typedef float f32x4 __attribute__((ext_vector_type(4)));

#define LN4 1.3862943611198906f

__device__ __forceinline__ void gl_lds16(const void* g, void* l) {
    typedef unsigned int u32;
    __builtin_amdgcn_global_load_lds(
        (const __attribute__((address_space(1))) u32*)(g),
        (__attribute__((address_space(3))) u32*)(l), 16, 0, 0);
}

// ===========================================================================
// Weight prep: fp32 W[27][CIN][CIN] -> f16 hi/lo transposed:
// WT[d][tap][ h(CIN) | l(CIN) ], d<CIN, tap<28 (tap 27 = zeros).
// ===========================================================================
template<int CIN>
__global__ __launch_bounds__(256) void prep_wt(
    const float* __restrict__ W, f16* __restrict__ dst)
{
    const int RE = 2 * CIN;
    int total = CIN * 28 * CIN;
    for (int i = blockIdx.x * 256 + threadIdx.x; i < total; i += gridDim.x * 256) {
        int d = i / (28 * CIN);
        int rem = i - d * (28 * CIN);
        int tap = rem / CIN;
        int c = rem - tap * CIN;
        float v = (tap < 27) ? W[(size_t)(tap * CIN + c) * CIN + d] : 0.f;
        f16 h = (f16)v;
        size_t base = (size_t)d * (28 * RE) + (size_t)tap * RE;
        dst[base + c] = h;
        dst[base + CIN + c] = (f16)(v - (float)h);
    }
}

// ===========================================================================
// B-fragment table for the fused P-projection (R11-verified layout):
// FG[((pass*KB+kb)*4+ct)][lane][8] f16.
// ===========================================================================
template<int CIN>
__global__ __launch_bounds__(256) void prep_gfrag(
    const float* __restrict__ Ws, f16* __restrict__ FG)
{
    constexpr int KB = (2 * CIN) / 32;
    int total = 2 * KB * 4 * 512;
    for (int i = blockIdx.x * 256 + threadIdx.x; i < total; i += gridDim.x * 256) {
        int j = i & 7;
        int lane = (i >> 3) & 63;
        int blk = i >> 9;
        int ct = blk & 3;
        int kbp = blk >> 2;
        int kb = kbp % KB;
        int pass = kbp / KB;
        int k = kb * 32 + ((lane >> 4) << 3) + j;
        int col = ct * 16 + (lane & 15);
        int c = (k < CIN) ? k : k - CIN;
        float w = 0.f;
        if (col < 54) {
            int t = col >> 1, jj = col & 1;
            w = Ws[((size_t)t * CIN + c) * 2 + jj];
        }
        f16 wh = (f16)w;
        FG[i] = (pass == 0) ? wh : ((k < CIN) ? (f16)(w - (float)wh) : (f16)0.f);
    }
}

// ===========================================================================
// Feature split (+optional gating): rows [h(CIN)|l(CIN)] f16, zero row at N.
// ===========================================================================
template<int CIN>
__global__ __launch_bounds__(256) void split_gated(
    const float* __restrict__ f, const float* __restrict__ mask,
    const int* __restrict__ parent, f16* __restrict__ Fc, int N)
{
    int i = blockIdx.x * 256 + threadIdx.x;
    if (i >= (N + 1) * CIN) return;
    int n = i / CIN, c = i - n * CIN;
    float v = 0.f;
    if (n < N) {
        bool a = parent ? (mask[parent[n]] != 0.f) : true;
        v = a ? f[i] : 0.f;
    }
    f16 h = (f16)v;
    Fc[(size_t)n * (2 * CIN) + c] = h;
    Fc[(size_t)n * (2 * CIN) + CIN + c] = (f16)(v - (float)h);
}

// fused act-gate + neighbor-flag expand (level 3)
__global__ __launch_bounds__(256) void gate_expand(
    const float* __restrict__ mask, const int* __restrict__ parent,
    const int* __restrict__ nbr, float* __restrict__ act,
    int* __restrict__ flag, int N)
{
    int m = blockIdx.x * 256 + threadIdx.x;
    if (m >= N) return;
    float a = mask[parent[m]];
    act[m] = a;
    if (a == 0.f) return;
    #pragma unroll 1
    for (int t = 0; t < 27; ++t) {
        int idx = nbr[(size_t)m * 27 + t];
        if (idx < N) flag[idx] = 1;
    }
}

// flag[nbr[m][t]] = 1 for every flagged source m (int src).
__global__ __launch_bounds__(256) void expand_kernel(
    const int* __restrict__ src, const int* __restrict__ nbr,
    int* __restrict__ flag, int N)
{
    int m = blockIdx.x * 256 + threadIdx.x;
    if (m >= N) return;
    if (src[m] == 0) return;
    #pragma unroll 1
    for (int t = 0; t < 27; ++t) {
        int idx = nbr[(size_t)m * 27 + t];
        if (idx < N) flag[idx] = 1;
    }
}

// wave-aggregated compaction: list[0..cnt) = rows with flag!=0
__global__ __launch_bounds__(256) void compact_kernel(
    const int* __restrict__ flag, int* __restrict__ list,
    int* __restrict__ cnt, int N)
{
    int i = blockIdx.x * 256 + threadIdx.x;
    int lane = threadIdx.x & 63;
    bool f = (i < N) && (flag[i] != 0);
    unsigned long long m = __ballot(f);
    int base = 0;
    if (lane == 0 && m) base = atomicAdd(cnt, __popcll(m));
    base = __shfl(base, 0);
    if (f) list[base + __popcll(m & ((1ull << lane) - 1ull))] = i;
}

// ===========================================================================
// Dense MFMA conv tile CIN->CIN (f16 hi/lo split, 3-term), 64 rows/block,
// 2 taps/phase, 14 phases + R15 fused P-projection epilogue.
// HOIST=true (CIN=48, NIT=5: +10 VGPR, measured R18: VALUBusy 35->15.6%,
// 92->84 us): staging source pointers computed once, advanced by STEP.
// HOIST=false (CIN=80, NIT=13 would cost +26 VGPR on top of KB=5's 80
// fragment VGPRs -> R12-style pressure; keep per-phase addressing).
// ===========================================================================
template<int CIN, bool HOIST>
__global__ __launch_bounds__(256, 3) void conv_tile(
    const f16* __restrict__ F, const int* __restrict__ nbr,
    const f16* __restrict__ WT, const f16* __restrict__ FG,
    float* __restrict__ P, int N, int nTiles)
{
    constexpr int RE = 2 * CIN;        // f16 per row (hi|lo)
    constexpr int KB = RE / 32;        // K chunks per phase
    constexpr int CT = CIN / 16;       // acc tiles over output cols
    constexpr int CPT = RE / 8;        // 16B chunks per tap row in BS
    constexpr int CPR = 2 * CPT;       // chunks per BS row (2 taps)
    constexpr int PB = CPR * 16;       // BS row bytes
    constexpr int LRE = RE + 8;        // padded LDS row (f16) for epilogue
    constexpr int NCH = CIN * CPR;     // staged 16B chunks per phase
    constexpr int NIT = (NCH + 255) / 256;
    constexpr int STEP = 2 * RE * 2;   // staging src advance per phase (bytes)
    __shared__ __align__(16) char BS[CIN * PB];

    const int t = threadIdx.x;
    const int lane = t & 63;
    const int l16 = lane & 15;
    const int quad = lane >> 4;
    const int wv = t >> 6;

    int q8 = (nTiles + 7) >> 3;
    int tile = (blockIdx.x & 7) * q8 + (blockIdx.x >> 3);
    if (tile >= nTiles) return;
    const int m0 = tile * 64;
    const int grow = m0 + wv * 16 + l16;

    f16x8 ahA[KB], alA[KB], ahB[KB], alB[KB];

    auto loadA = [&](int p, f16x8 (&ah)[KB], f16x8 (&al)[KB]) {
        int i0 = N, i1 = N;
        if (grow < N) {
            i0 = nbr[(size_t)grow * 27 + 2 * p];
            if (2 * p + 1 < 27) i1 = nbr[(size_t)grow * 27 + 2 * p + 1];
        }
        #pragma unroll
        for (int kb = 0; kb < KB; ++kb) {
            int ko = kb * 32 + quad * 8;
            int ts = ko >= CIN;
            int c2 = ko - (ts ? CIN : 0);
            const f16* ap = F + (size_t)(ts ? i1 : i0) * RE + c2;
            ah[kb] = *(const f16x8*)ap;
            al[kb] = *(const f16x8*)(ap + CIN);
        }
    };

    // hoisted staging source pointers (phase 0); advance by STEP per phase
    const char* ssrc[HOIST ? NIT : 1];
    if constexpr (HOIST) {
        #pragma unroll
        for (int it = 0; it < NIT; ++it) {
            int i = t + it * 256;
            int iv = (i < NCH) ? i : 0;
            int d = iv / CPR, cs = iv - d * CPR;
            int c = (cs & ~7) | ((cs ^ d) & 7);
            int tp = c / CPT, cc = c - tp * CPT;
            ssrc[it] = (const char*)WT + (((size_t)d * 28 + tp) * RE + cc * 8) * 2;
        }
    }

    auto stageB = [&](int p) {
        if constexpr (HOIST) {
            #pragma unroll
            for (int it = 0; it < NIT; ++it) {
                int i = t + it * 256;
                if (i < NCH) gl_lds16(ssrc[it], BS + (size_t)i * 16);
                ssrc[it] += STEP;
            }
        } else {
            for (int i = t; i < NCH; i += 256) {
                int d = i / CPR, cs = i - d * CPR;
                int c = (cs & ~7) | ((cs ^ d) & 7);
                int tp = c / CPT, cc = c - tp * CPT;
                gl_lds16((const char*)WT + (((size_t)d * 28 + 2 * p + tp) * RE + cc * 8) * 2,
                         BS + (size_t)i * 16);
            }
        }
    };

    f32x4 acc[CT];
    #pragma unroll
    for (int ct = 0; ct < CT; ++ct) acc[ct] = (f32x4){0.f, 0.f, 0.f, 0.f};

    auto compute = [&](f16x8 (&ah)[KB], f16x8 (&al)[KB]) {
        #pragma unroll
        for (int kb = 0; kb < KB; ++kb) {
            int ko = kb * 32 + quad * 8;
            int ts = ko >= CIN;
            int c2 = ko - (ts ? CIN : 0);
            int ch = ts * CPT + c2 / 8;
            int chl = ch + CIN / 8;
            #pragma unroll
            for (int ct = 0; ct < CT; ++ct) {
                int drow = ct * 16 + l16;
                int sb = (ch & ~7) | ((ch ^ drow) & 7);
                int sbl = (chl & ~7) | ((chl ^ drow) & 7);
                f16x8 bh = *(const f16x8*)(BS + drow * PB + sb * 16);
                f16x8 bl = *(const f16x8*)(BS + drow * PB + sbl * 16);
                acc[ct] = __builtin_amdgcn_mfma_f32_16x16x32_f16(ah[kb], bh, acc[ct], 0, 0, 0);
                acc[ct] = __builtin_amdgcn_mfma_f32_16x16x32_f16(al[kb], bh, acc[ct], 0, 0, 0);
                acc[ct] = __builtin_amdgcn_mfma_f32_16x16x32_f16(ah[kb], bl, acc[ct], 0, 0, 0);
            }
        }
    };

    loadA(0, ahA, alA);
    #pragma unroll 1
    for (int p = 0; p < 14; p += 2) {
        __syncthreads();
        stageB(p);
        loadA(p + 1, ahB, alB);          // p+1 <= 13 always
        __syncthreads();
        compute(ahA, alA);

        __syncthreads();
        stageB(p + 1);
        if (p + 2 < 14) loadA(p + 2, ahA, alA);
        __syncthreads();
        compute(ahB, alB);
    }

    // ---- fused P-projection epilogue (R15-verified) ----
    __syncthreads();                       // BS free for reuse (all waves done)
    f16* LW = (f16*)BS + (size_t)wv * 16 * LRE;   // wave-private 16-row region

    // dump acc rows as the SAME hi/lo f16 split the old Y buffer used
    #pragma unroll
    for (int ct = 0; ct < CT; ++ct) {
        #pragma unroll
        for (int r = 0; r < 4; ++r) {
            int wrow = quad * 4 + r;
            int d = ct * 16 + l16;
            float v = acc[ct][r];
            f16 h = (f16)v;
            LW[wrow * LRE + d] = h;
            LW[wrow * LRE + CIN + d] = (f16)(v - (float)h);
        }
    }
    // wave-local RAW: same wave reads its own region (lgkmcnt ordering)

    f32x4 pa[4];
    #pragma unroll
    for (int ct = 0; ct < 4; ++ct) pa[ct] = (f32x4){0.f, 0.f, 0.f, 0.f};

    #pragma unroll
    for (int kb = 0; kb < KB; ++kb) {
        f16x8 a = *(const f16x8*)(LW + l16 * LRE + kb * 32 + quad * 8);
        #pragma unroll
        for (int ct = 0; ct < 4; ++ct) {
            f16x8 b = *(const f16x8*)(FG + ((size_t)((0 * KB + kb) * 4 + ct)) * 512 + lane * 8);
            pa[ct] = __builtin_amdgcn_mfma_f32_16x16x32_f16(a, b, pa[ct], 0, 0, 0);
        }
        #pragma unroll
        for (int ct = 0; ct < 4; ++ct) {
            f16x8 b = *(const f16x8*)(FG + ((size_t)((1 * KB + kb) * 4 + ct)) * 512 + lane * 8);
            pa[ct] = __builtin_amdgcn_mfma_f32_16x16x32_f16(a, b, pa[ct], 0, 0, 0);
        }
    }

    #pragma unroll
    for (int ct = 0; ct < 4; ++ct) {
        int col = ct * 16 + l16;
        if (col < 54) {
            #pragma unroll
            for (int r = 0; r < 4; ++r) {
                int row = m0 + wv * 16 + quad * 4 + r;
                if (row < N) P[(size_t)row * 54 + col] = pa[ct][r];
            }
        }
    }
}

// ===========================================================================
// Fused score-gather + ppn finalize (R11-verified).
// ===========================================================================
__global__ __launch_bounds__(256) void finalize_gather(
    const int* __restrict__ coords, const float* __restrict__ P,
    const int* __restrict__ nbr, float* __restrict__ ppn,
    float* __restrict__ mask, int N)
{
    int n = blockIdx.x * 256 + threadIdx.x;
    if (n >= N) return;
    float s0 = 0.f, s1 = 0.f;
    #pragma unroll
    for (int t = 0; t < 27; ++t) {
        int idx = nbr[(size_t)n * 27 + t];
        if (idx < N) {
            float2 v = *(const float2*)(P + (size_t)idx * 54 + 2 * t);
            s0 += v.x; s1 += v.y;
        }
    }
    ppn[(size_t)n * 6 + 0] = (float)coords[(size_t)n * 4 + 0];
    ppn[(size_t)n * 6 + 1] = (float)coords[(size_t)n * 4 + 1];
    ppn[(size_t)n * 6 + 2] = (float)coords[(size_t)n * 4 + 2];
    ppn[(size_t)n * 6 + 3] = (float)coords[(size_t)n * 4 + 3];
    ppn[(size_t)n * 6 + 4] = s0;
    ppn[(size_t)n * 6 + 5] = s1;
    mask[n] = (s1 - s0 > LN4) ? 1.0f : 0.0f;
}

// ===========================================================================
// Level 3 compute kernels over compacted lists (Round-0 measured, unchanged).
// ===========================================================================
__global__ __launch_bounds__(256) void lvl3_z_compute(
    const float* __restrict__ feat3, const int* __restrict__ nbr3,
    const float* __restrict__ act, const float* __restrict__ W3,
    float* __restrict__ z, const int* __restrict__ list,
    const int* __restrict__ cnt, int N)
{
    const int lane = threadIdx.x & 63;
    const int wid0 = (blockIdx.x * 256 + threadIdx.x) >> 6;
    const int nw = (gridDim.x * 256) >> 6;
    const int count = *cnt;
    const int c = lane;

    for (int w = wid0; w < count; w += nw) {
        const int n = list[w];
        int ld = N;
        if (lane < 27) ld = nbr3[(size_t)n * 27 + lane];
        bool valid = (lane < 27) && (ld < N);
        float a = valid ? act[ld] : 0.f;
        unsigned long long m = __ballot(a != 0.f);

        float acc = 0.f;
        while (m) {
            int t = __ffsll(m) - 1; m &= m - 1;
            int idx = __shfl(ld, t);
            const float4* f4 = (const float4*)(feat3 + (size_t)idx * 16);
            const float* wgt = W3 + (size_t)t * 256;
            #pragma unroll
            for (int q = 0; q < 4; ++q) {
                float4 fv = f4[q];
                if (c < 16) {
                    acc += fv.x * wgt[(4 * q + 0) * 16 + c];
                    acc += fv.y * wgt[(4 * q + 1) * 16 + c];
                    acc += fv.z * wgt[(4 * q + 2) * 16 + c];
                    acc += fv.w * wgt[(4 * q + 3) * 16 + c];
                }
            }
        }
        if (lane < 16) z[(size_t)n * 16 + lane] = acc;
    }
}

__global__ __launch_bounds__(256) void lvl3_pts_compute(
    const float* __restrict__ z, const int* __restrict__ zflag,
    const int* __restrict__ nbr3,
    const float* __restrict__ Wp, const float* __restrict__ Ws,
    const float* __restrict__ Wt, float* __restrict__ points,
    const int* __restrict__ list, const int* __restrict__ cnt, int N)
{
    const int lane = threadIdx.x & 63;
    const int wid0 = (blockIdx.x * 256 + threadIdx.x) >> 6;
    const int nw = (gridDim.x * 256) >> 6;
    const int count = *cnt;
    const int c = lane;

    for (int w = wid0; w < count; w += nw) {
        const int n = list[w];
        int ld = N;
        if (lane < 27) ld = nbr3[(size_t)n * 27 + lane];
        bool valid = (lane < 27) && (ld < N);
        int zf = valid ? zflag[ld] : 0;
        unsigned long long m = __ballot(zf != 0);

        float acc = 0.f;
        while (m) {
            int t = __ffsll(m) - 1; m &= m - 1;
            int idx = __shfl(ld, t);
            const float4* z4 = (const float4*)(z + (size_t)idx * 16);
            #pragma unroll
            for (int q = 0; q < 4; ++q) {
                float4 zv = z4[q];
                if (c < 10) {
                    #pragma unroll
                    for (int j = 0; j < 4; ++j) {
                        int k = 4 * q + j;
                        int kc = t * 16 + k;
                        float wv = (c < 3) ? Wp[(size_t)kc * 3 + c]
                                 : (c < 5) ? Ws[(size_t)kc * 2 + (c - 3)]
                                           : Wt[(size_t)kc * 5 + (c - 5)];
                        float zj = (j == 0) ? zv.x : (j == 1) ? zv.y : (j == 2) ? zv.z : zv.w;
                        acc += zj * wv;
                    }
                }
            }
        }
        if (lane < 10) points[(size_t)n * 10 + lane] = acc;
    }
}

// ===========================================================================
extern "C" void kernel_launch(void* const* d_in, const int* in_sizes, int n_in,
                              void* d_out, int out_size, void* d_ws, size_t ws_size,
                              hipStream_t stream)
{
    const float* feat1 = (const float*)d_in[0];
    const float* feat2 = (const float*)d_in[1];
    const float* feat3 = (const float*)d_in[2];
    const float* W1    = (const float*)d_in[3];
    const float* W1s   = (const float*)d_in[4];
    const float* W2    = (const float*)d_in[5];
    const float* W2s   = (const float*)d_in[6];
    const float* W3    = (const float*)d_in[7];
    const float* W3p   = (const float*)d_in[8];
    const float* W3s   = (const float*)d_in[9];
    const float* W3t   = (const float*)d_in[10];
    const int* nbr1    = (const int*)d_in[11];
    const int* nbr2    = (const int*)d_in[12];
    const int* nbr3    = (const int*)d_in[13];
    const int* parent2 = (const int*)d_in[14];
    const int* parent3 = (const int*)d_in[15];
    const int* coords1 = (const int*)d_in[16];
    const int* coords2 = (const int*)d_in[17];

    const int N1 = in_sizes[0] / 80;
    const int N2 = in_sizes[1] / 48;
    const int N3 = in_sizes[2] / 16;

    float* out = (float*)d_out;
    float* o_points = out;                              // [N3,10]
    float* o_ppn1   = o_points + (size_t)N3 * 10;       // [N1,6]
    float* o_ppn2   = o_ppn1 + (size_t)N1 * 6;          // [N2,6]
    float* o_mask1  = o_ppn2 + (size_t)N2 * 6;          // [N1]
    float* o_mask2  = o_mask1 + (size_t)N1;             // [N2]

    char* wp = (char*)d_ws;
    auto alloc = [&](size_t bytes) -> char* {
        char* r = wp; wp += (bytes + 255) & ~(size_t)255; return r;
    };
    auto A256 = [](size_t b) { return (b + 255) & ~(size_t)255; };

    f16*   WT1 = (f16*)alloc((size_t)80 * 28 * 160 * 2);
    f16*   WT2 = (f16*)alloc((size_t)48 * 28 * 96 * 2);
    f16*   FG1 = (f16*)alloc((size_t)2 * 5 * 4 * 512 * 2);
    f16*   FG2 = (f16*)alloc((size_t)2 * 3 * 4 * 512 * 2);
    float* act3 = (float*)alloc((size_t)N3 * 4);
    int*   cnts = (int*)alloc(2 * 4);    // [cntz, cntp]

    // Fa: split features (levels 1,2 sequentially)
    size_t fa1 = (size_t)(N1 + 1) * 320, fa2 = (size_t)(N2 + 1) * 192;
    f16* Fa = (f16*)alloc(fa1 > fa2 ? fa1 : fa2);

    // P union: P projection (levels 1,2), then level-3 flags/lists/zbuf
    size_t pmax = (size_t)(N1 > N2 ? N1 : N2) * 216 + 256;
    size_t l3b = 4 * A256((size_t)N3 * 4) + A256((size_t)N3 * 16 * 4);
    size_t szP = pmax > l3b ? pmax : l3b;
    char* Pu = alloc(szP);
    float* P = (float*)Pu;
    char* q3 = Pu;
    int*   flagz = (int*)q3; q3 += A256((size_t)N3 * 4);
    int*   listz = (int*)q3; q3 += A256((size_t)N3 * 4);
    int*   flagp = (int*)q3; q3 += A256((size_t)N3 * 4);
    int*   listp = (int*)q3; q3 += A256((size_t)N3 * 4);
    float* zbuf  = (float*)q3;

    auto cdiv = [](long long a, long long b) { return (int)((a + b - 1) / b); };

    hipMemsetAsync(cnts, 0, 2 * 4, stream);
    hipMemsetAsync(o_points, 0, (size_t)N3 * 10 * 4, stream);

    // ---- weight prep ----
    prep_wt<80><<<700, 256, 0, stream>>>(W1, WT1);
    prep_wt<48><<<cdiv(48 * 28 * 48, 256), 256, 0, stream>>>(W2, WT2);
    prep_gfrag<80><<<80, 256, 0, stream>>>(W1s, FG1);
    prep_gfrag<48><<<48, 256, 0, stream>>>(W2s, FG2);

    // ---- level 1: fused conv+P-projection -> fused finalize ----
    {
        int Tc = cdiv(N1, 64);
        dim3 gc(8 * cdiv(Tc, 8));
        split_gated<80><<<cdiv((size_t)(N1 + 1) * 80, 256), 256, 0, stream>>>(
            feat1, nullptr, nullptr, Fa, N1);
        conv_tile<80, false><<<gc, 256, 0, stream>>>(Fa, nbr1, WT1, FG1, P, N1, Tc);
        finalize_gather<<<cdiv(N1, 256), 256, 0, stream>>>(
            coords1, P, nbr1, o_ppn1, o_mask1, N1);
    }

    // ---- level 2: fused conv+P-projection -> fused finalize ----
    {
        int Tc = cdiv(N2, 64);
        dim3 gc(8 * cdiv(Tc, 8));
        split_gated<48><<<cdiv((size_t)(N2 + 1) * 48, 256), 256, 0, stream>>>(
            feat2, o_mask1, parent2, Fa, N2);
        conv_tile<48, true><<<gc, 256, 0, stream>>>(Fa, nbr2, WT2, FG2, P, N2, Tc);
        finalize_gather<<<cdiv(N2, 256), 256, 0, stream>>>(
            coords2, P, nbr2, o_ppn2, o_mask2, N2);
    }

    // ---- level 3: fused gate+expand -> compact -> z -> expand -> compact -> pts
    hipMemsetAsync(flagz, 0, (size_t)N3 * 4, stream);
    hipMemsetAsync(flagp, 0, (size_t)N3 * 4, stream);
    gate_expand<<<cdiv(N3, 256), 256, 0, stream>>>(o_mask2, parent3, nbr3,
                                                   act3, flagz, N3);
    compact_kernel<<<cdiv(N3, 256), 256, 0, stream>>>(flagz, listz, &cnts[0], N3);
    lvl3_z_compute<<<2048, 256, 0, stream>>>(feat3, nbr3, act3, W3, zbuf,
                                             listz, &cnts[0], N3);
    expand_kernel<<<cdiv(N3, 256), 256, 0, stream>>>(flagz, nbr3, flagp, N3);
    compact_kernel<<<cdiv(N3, 256), 256, 0, stream>>>(flagp, listp, &cnts[1], N3);
    lvl3_pts_compute<<<2048, 256, 0, stream>>>(zbuf, flagz, nbr3, W3p, W3s, W3t,
                                               o_points, listp, &cnts[1], N3);
}

// Round 15
// 328.953 us; speedup vs baseline: 1.1085x; 1.0374x over previous
//
#include <hip/hip_runtime.h>

typedef _Float16 f16;
typedef _Float16 f16x8 __attribute__((ext_vector_type(8)));
typedef float f32x4 __attribute__((ext_vector_type(4)));

#define LN4 1.3862943611198906f

__device__ __forceinline__ void gl_lds16(const void* g, void* l) {
    typedef unsigned int u32;
    __builtin_amdgcn_global_load_lds(
        (const __attribute__((address_space(1))) u32*)(g),
        (__attribute__((address_space(3))) u32*)(l), 16, 0, 0);
}

// ===========================================================================
// Weight prep: fp32 W[27][CIN][CIN] -> f16 hi/lo transposed:
// WT[d][tap][ h(CIN) | l(CIN) ], d<CIN, tap<28 (tap 27 = zeros).
// ===========================================================================
template<int CIN>
__global__ __launch_bounds__(256) void prep_wt(
    const float* __restrict__ W, f16* __restrict__ dst)
{
    const int RE = 2 * CIN;
    int total = CIN * 28 * CIN;
    for (int i = blockIdx.x * 256 + threadIdx.x; i < total; i += gridDim.x * 256) {
        int d = i / (28 * CIN);
        int rem = i - d * (28 * CIN);
        int tap = rem / CIN;
        int c = rem - tap * CIN;
        float v = (tap < 27) ? W[(size_t)(tap * CIN + c) * CIN + d] : 0.f;
        f16 h = (f16)v;
        size_t base = (size_t)d * (28 * RE) + (size_t)tap * RE;
        dst[base + c] = h;
        dst[base + CIN + c] = (f16)(v - (float)h);
    }
}

// ===========================================================================
// B-fragment table for the fused P-projection (R11-verified layout):
// FG[((pass*KB+kb)*4+ct)][lane][8] f16.
// ===========================================================================
template<int CIN>
__global__ __launch_bounds__(256) void prep_gfrag(
    const float* __restrict__ Ws, f16* __restrict__ FG)
{
    constexpr int KB = (2 * CIN) / 32;
    int total = 2 * KB * 4 * 512;
    for (int i = blockIdx.x * 256 + threadIdx.x; i < total; i += gridDim.x * 256) {
        int j = i & 7;
        int lane = (i >> 3) & 63;
        int blk = i >> 9;
        int ct = blk & 3;
        int kbp = blk >> 2;
        int kb = kbp % KB;
        int pass = kbp / KB;
        int k = kb * 32 + ((lane >> 4) << 3) + j;
        int col = ct * 16 + (lane & 15);
        int c = (k < CIN) ? k : k - CIN;
        float w = 0.f;
        if (col < 54) {
            int t = col >> 1, jj = col & 1;
            w = Ws[((size_t)t * CIN + c) * 2 + jj];
        }
        f16 wh = (f16)w;
        FG[i] = (pass == 0) ? wh : ((k < CIN) ? (f16)(w - (float)wh) : (f16)0.f);
    }
}

// ===========================================================================
// Feature split (+optional gating): rows [h(CIN)|l(CIN)] f16, zero row at N.
// ===========================================================================
template<int CIN>
__global__ __launch_bounds__(256) void split_gated(
    const float* __restrict__ f, const float* __restrict__ mask,
    const int* __restrict__ parent, f16* __restrict__ Fc, int N)
{
    int i = blockIdx.x * 256 + threadIdx.x;
    if (i >= (N + 1) * CIN) return;
    int n = i / CIN, c = i - n * CIN;
    float v = 0.f;
    if (n < N) {
        bool a = parent ? (mask[parent[n]] != 0.f) : true;
        v = a ? f[i] : 0.f;
    }
    f16 h = (f16)v;
    Fc[(size_t)n * (2 * CIN) + c] = h;
    Fc[(size_t)n * (2 * CIN) + CIN + c] = (f16)(v - (float)h);
}

// fused act-gate + neighbor-flag expand (level 3)
__global__ __launch_bounds__(256) void gate_expand(
    const float* __restrict__ mask, const int* __restrict__ parent,
    const int* __restrict__ nbr, float* __restrict__ act,
    int* __restrict__ flag, int N)
{
    int m = blockIdx.x * 256 + threadIdx.x;
    if (m >= N) return;
    float a = mask[parent[m]];
    act[m] = a;
    if (a == 0.f) return;
    #pragma unroll 1
    for (int t = 0; t < 27; ++t) {
        int idx = nbr[(size_t)m * 27 + t];
        if (idx < N) flag[idx] = 1;
    }
}

// flag[nbr[m][t]] = 1 for every flagged source m (int src).
__global__ __launch_bounds__(256) void expand_kernel(
    const int* __restrict__ src, const int* __restrict__ nbr,
    int* __restrict__ flag, int N)
{
    int m = blockIdx.x * 256 + threadIdx.x;
    if (m >= N) return;
    if (src[m] == 0) return;
    #pragma unroll 1
    for (int t = 0; t < 27; ++t) {
        int idx = nbr[(size_t)m * 27 + t];
        if (idx < N) flag[idx] = 1;
    }
}

// wave-aggregated compaction: list[0..cnt) = rows with flag!=0
__global__ __launch_bounds__(256) void compact_kernel(
    const int* __restrict__ flag, int* __restrict__ list,
    int* __restrict__ cnt, int N)
{
    int i = blockIdx.x * 256 + threadIdx.x;
    int lane = threadIdx.x & 63;
    bool f = (i < N) && (flag[i] != 0);
    unsigned long long m = __ballot(f);
    int base = 0;
    if (lane == 0 && m) base = atomicAdd(cnt, __popcll(m));
    base = __shfl(base, 0);
    if (f) list[base + __popcll(m & ((1ull << lane) - 1ull))] = i;
}

// ===========================================================================
// Dense MFMA conv tile CIN->CIN (f16 hi/lo split, 3-term), 64 rows/block,
// 2 taps/phase, 14 phases + R15 fused P-projection epilogue.
// HOIST=true (CIN=48, measured R18/R19: VALUBusy 35->15.6%, -8 us).
// HOIST=false (CIN=80: NIT=13 pointer regs -> R12-style pressure; measured
// R18/R19: keep per-phase addressing).
// ===========================================================================
template<int CIN, bool HOIST>
__global__ __launch_bounds__(256, 3) void conv_tile(
    const f16* __restrict__ F, const int* __restrict__ nbr,
    const f16* __restrict__ WT, const f16* __restrict__ FG,
    float* __restrict__ P, int N, int nTiles)
{
    constexpr int RE = 2 * CIN;        // f16 per row (hi|lo)
    constexpr int KB = RE / 32;        // K chunks per phase
    constexpr int CT = CIN / 16;       // acc tiles over output cols
    constexpr int CPT = RE / 8;        // 16B chunks per tap row in BS
    constexpr int CPR = 2 * CPT;       // chunks per BS row (2 taps)
    constexpr int PB = CPR * 16;       // BS row bytes
    constexpr int LRE = RE + 8;        // padded LDS row (f16) for epilogue
    constexpr int NCH = CIN * CPR;     // staged 16B chunks per phase
    constexpr int NIT = (NCH + 255) / 256;
    constexpr int STEP = 2 * RE * 2;   // staging src advance per phase (bytes)
    __shared__ __align__(16) char BS[CIN * PB];

    const int t = threadIdx.x;
    const int lane = t & 63;
    const int l16 = lane & 15;
    const int quad = lane >> 4;
    const int wv = t >> 6;

    int q8 = (nTiles + 7) >> 3;
    int tile = (blockIdx.x & 7) * q8 + (blockIdx.x >> 3);
    if (tile >= nTiles) return;
    const int m0 = tile * 64;
    const int grow = m0 + wv * 16 + l16;

    f16x8 ahA[KB], alA[KB], ahB[KB], alB[KB];

    auto loadA = [&](int p, f16x8 (&ah)[KB], f16x8 (&al)[KB]) {
        int i0 = N, i1 = N;
        if (grow < N) {
            i0 = nbr[(size_t)grow * 27 + 2 * p];
            if (2 * p + 1 < 27) i1 = nbr[(size_t)grow * 27 + 2 * p + 1];
        }
        #pragma unroll
        for (int kb = 0; kb < KB; ++kb) {
            int ko = kb * 32 + quad * 8;
            int ts = ko >= CIN;
            int c2 = ko - (ts ? CIN : 0);
            const f16* ap = F + (size_t)(ts ? i1 : i0) * RE + c2;
            ah[kb] = *(const f16x8*)ap;
            al[kb] = *(const f16x8*)(ap + CIN);
        }
    };

    // hoisted staging source pointers (phase 0); advance by STEP per phase
    const char* ssrc[HOIST ? NIT : 1];
    if constexpr (HOIST) {
        #pragma unroll
        for (int it = 0; it < NIT; ++it) {
            int i = t + it * 256;
            int iv = (i < NCH) ? i : 0;
            int d = iv / CPR, cs = iv - d * CPR;
            int c = (cs & ~7) | ((cs ^ d) & 7);
            int tp = c / CPT, cc = c - tp * CPT;
            ssrc[it] = (const char*)WT + (((size_t)d * 28 + tp) * RE + cc * 8) * 2;
        }
    }

    auto stageB = [&](int p) {
        if constexpr (HOIST) {
            #pragma unroll
            for (int it = 0; it < NIT; ++it) {
                int i = t + it * 256;
                if (i < NCH) gl_lds16(ssrc[it], BS + (size_t)i * 16);
                ssrc[it] += STEP;
            }
        } else {
            for (int i = t; i < NCH; i += 256) {
                int d = i / CPR, cs = i - d * CPR;
                int c = (cs & ~7) | ((cs ^ d) & 7);
                int tp = c / CPT, cc = c - tp * CPT;
                gl_lds16((const char*)WT + (((size_t)d * 28 + 2 * p + tp) * RE + cc * 8) * 2,
                         BS + (size_t)i * 16);
            }
        }
    };

    f32x4 acc[CT];
    #pragma unroll
    for (int ct = 0; ct < CT; ++ct) acc[ct] = (f32x4){0.f, 0.f, 0.f, 0.f};

    auto compute = [&](f16x8 (&ah)[KB], f16x8 (&al)[KB]) {
        #pragma unroll
        for (int kb = 0; kb < KB; ++kb) {
            int ko = kb * 32 + quad * 8;
            int ts = ko >= CIN;
            int c2 = ko - (ts ? CIN : 0);
            int ch = ts * CPT + c2 / 8;
            int chl = ch + CIN / 8;
            #pragma unroll
            for (int ct = 0; ct < CT; ++ct) {
                int drow = ct * 16 + l16;
                int sb = (ch & ~7) | ((ch ^ drow) & 7);
                int sbl = (chl & ~7) | ((chl ^ drow) & 7);
                f16x8 bh = *(const f16x8*)(BS + drow * PB + sb * 16);
                f16x8 bl = *(const f16x8*)(BS + drow * PB + sbl * 16);
                acc[ct] = __builtin_amdgcn_mfma_f32_16x16x32_f16(ah[kb], bh, acc[ct], 0, 0, 0);
                acc[ct] = __builtin_amdgcn_mfma_f32_16x16x32_f16(al[kb], bh, acc[ct], 0, 0, 0);
                acc[ct] = __builtin_amdgcn_mfma_f32_16x16x32_f16(ah[kb], bl, acc[ct], 0, 0, 0);
            }
        }
    };

    loadA(0, ahA, alA);
    #pragma unroll 1
    for (int p = 0; p < 14; p += 2) {
        __syncthreads();
        stageB(p);
        loadA(p + 1, ahB, alB);          // p+1 <= 13 always
        __syncthreads();
        compute(ahA, alA);

        __syncthreads();
        stageB(p + 1);
        if (p + 2 < 14) loadA(p + 2, ahA, alA);
        __syncthreads();
        compute(ahB, alB);
    }

    // ---- fused P-projection epilogue (R15-verified) ----
    __syncthreads();                       // BS free for reuse (all waves done)
    f16* LW = (f16*)BS + (size_t)wv * 16 * LRE;   // wave-private 16-row region

    // dump acc rows as the SAME hi/lo f16 split the old Y buffer used
    #pragma unroll
    for (int ct = 0; ct < CT; ++ct) {
        #pragma unroll
        for (int r = 0; r < 4; ++r) {
            int wrow = quad * 4 + r;
            int d = ct * 16 + l16;
            float v = acc[ct][r];
            f16 h = (f16)v;
            LW[wrow * LRE + d] = h;
            LW[wrow * LRE + CIN + d] = (f16)(v - (float)h);
        }
    }
    // wave-local RAW: same wave reads its own region (lgkmcnt ordering)

    f32x4 pa[4];
    #pragma unroll
    for (int ct = 0; ct < 4; ++ct) pa[ct] = (f32x4){0.f, 0.f, 0.f, 0.f};

    #pragma unroll
    for (int kb = 0; kb < KB; ++kb) {
        f16x8 a = *(const f16x8*)(LW + l16 * LRE + kb * 32 + quad * 8);
        #pragma unroll
        for (int ct = 0; ct < 4; ++ct) {
            f16x8 b = *(const f16x8*)(FG + ((size_t)((0 * KB + kb) * 4 + ct)) * 512 + lane * 8);
            pa[ct] = __builtin_amdgcn_mfma_f32_16x16x32_f16(a, b, pa[ct], 0, 0, 0);
        }
        #pragma unroll
        for (int ct = 0; ct < 4; ++ct) {
            f16x8 b = *(const f16x8*)(FG + ((size_t)((1 * KB + kb) * 4 + ct)) * 512 + lane * 8);
            pa[ct] = __builtin_amdgcn_mfma_f32_16x16x32_f16(a, b, pa[ct], 0, 0, 0);
        }
    }

    #pragma unroll
    for (int ct = 0; ct < 4; ++ct) {
        int col = ct * 16 + l16;
        if (col < 54) {
            #pragma unroll
            for (int r = 0; r < 4; ++r) {
                int row = m0 + wv * 16 + quad * 4 + r;
                if (row < N) P[(size_t)row * 54 + col] = pa[ct][r];
            }
        }
    }
}

// ===========================================================================
// Fused score-gather + ppn finalize. R20: wave-per-row — coalesced 27-lane
// nbr read + parallel P gathers + 6-step shuffle reduce (replaces 27
// sequential strided loads per thread).
// ===========================================================================
__global__ __launch_bounds__(256) void finalize_gather(
    const int* __restrict__ coords, const float* __restrict__ P,
    const int* __restrict__ nbr, float* __restrict__ ppn,
    float* __restrict__ mask, int N)
{
    const int lane = threadIdx.x & 63;
    const int wid0 = (blockIdx.x * 256 + threadIdx.x) >> 6;
    const int nw = (gridDim.x * 256) >> 6;

    for (int n = wid0; n < N; n += nw) {
        float s0 = 0.f, s1 = 0.f;
        if (lane < 27) {
            int idx = nbr[(size_t)n * 27 + lane];
            if (idx < N) {
                float2 v = *(const float2*)(P + (size_t)idx * 54 + 2 * lane);
                s0 = v.x; s1 = v.y;
            }
        }
        #pragma unroll
        for (int s = 32; s; s >>= 1) {
            s0 += __shfl_down(s0, s);
            s1 += __shfl_down(s1, s);
        }
        if (lane == 0) {
            ppn[(size_t)n * 6 + 0] = (float)coords[(size_t)n * 4 + 0];
            ppn[(size_t)n * 6 + 1] = (float)coords[(size_t)n * 4 + 1];
            ppn[(size_t)n * 6 + 2] = (float)coords[(size_t)n * 4 + 2];
            ppn[(size_t)n * 6 + 3] = (float)coords[(size_t)n * 4 + 3];
            ppn[(size_t)n * 6 + 4] = s0;
            ppn[(size_t)n * 6 + 5] = s1;
            mask[n] = (s1 - s0 > LN4) ? 1.0f : 0.0f;
        }
    }
}

// ===========================================================================
// Level 3 compute kernels over compacted lists (Round-0 measured, unchanged).
// ===========================================================================
__global__ __launch_bounds__(256) void lvl3_z_compute(
    const float* __restrict__ feat3, const int* __restrict__ nbr3,
    const float* __restrict__ act, const float* __restrict__ W3,
    float* __restrict__ z, const int* __restrict__ list,
    const int* __restrict__ cnt, int N)
{
    const int lane = threadIdx.x & 63;
    const int wid0 = (blockIdx.x * 256 + threadIdx.x) >> 6;
    const int nw = (gridDim.x * 256) >> 6;
    const int count = *cnt;
    const int c = lane;

    for (int w = wid0; w < count; w += nw) {
        const int n = list[w];
        int ld = N;
        if (lane < 27) ld = nbr3[(size_t)n * 27 + lane];
        bool valid = (lane < 27) && (ld < N);
        float a = valid ? act[ld] : 0.f;
        unsigned long long m = __ballot(a != 0.f);

        float acc = 0.f;
        while (m) {
            int t = __ffsll(m) - 1; m &= m - 1;
            int idx = __shfl(ld, t);
            const float4* f4 = (const float4*)(feat3 + (size_t)idx * 16);
            const float* wgt = W3 + (size_t)t * 256;
            #pragma unroll
            for (int q = 0; q < 4; ++q) {
                float4 fv = f4[q];
                if (c < 16) {
                    acc += fv.x * wgt[(4 * q + 0) * 16 + c];
                    acc += fv.y * wgt[(4 * q + 1) * 16 + c];
                    acc += fv.z * wgt[(4 * q + 2) * 16 + c];
                    acc += fv.w * wgt[(4 * q + 3) * 16 + c];
                }
            }
        }
        if (lane < 16) z[(size_t)n * 16 + lane] = acc;
    }
}

__global__ __launch_bounds__(256) void lvl3_pts_compute(
    const float* __restrict__ z, const int* __restrict__ zflag,
    const int* __restrict__ nbr3,
    const float* __restrict__ Wp, const float* __restrict__ Ws,
    const float* __restrict__ Wt, float* __restrict__ points,
    const int* __restrict__ list, const int* __restrict__ cnt, int N)
{
    const int lane = threadIdx.x & 63;
    const int wid0 = (blockIdx.x * 256 + threadIdx.x) >> 6;
    const int nw = (gridDim.x * 256) >> 6;
    const int count = *cnt;
    const int c = lane;

    for (int w = wid0; w < count; w += nw) {
        const int n = list[w];
        int ld = N;
        if (lane < 27) ld = nbr3[(size_t)n * 27 + lane];
        bool valid = (lane < 27) && (ld < N);
        int zf = valid ? zflag[ld] : 0;
        unsigned long long m = __ballot(zf != 0);

        float acc = 0.f;
        while (m) {
            int t = __ffsll(m) - 1; m &= m - 1;
            int idx = __shfl(ld, t);
            const float4* z4 = (const float4*)(z + (size_t)idx * 16);
            #pragma unroll
            for (int q = 0; q < 4; ++q) {
                float4 zv = z4[q];
                if (c < 10) {
                    #pragma unroll
                    for (int j = 0; j < 4; ++j) {
                        int k = 4 * q + j;
                        int kc = t * 16 + k;
                        float wv = (c < 3) ? Wp[(size_t)kc * 3 + c]
                                 : (c < 5) ? Ws[(size_t)kc * 2 + (c - 3)]
                                           : Wt[(size_t)kc * 5 + (c - 5)];
                        float zj = (j == 0) ? zv.x : (j == 1) ? zv.y : (j == 2) ? zv.z : zv.w;
                        acc += zj * wv;
                    }
                }
            }
        }
        if (lane < 10) points[(size_t)n * 10 + lane] = acc;
    }
}

// ===========================================================================
extern "C" void kernel_launch(void* const* d_in, const int* in_sizes, int n_in,
                              void* d_out, int out_size, void* d_ws, size_t ws_size,
                              hipStream_t stream)
{
    const float* feat1 = (const float*)d_in[0];
    const float* feat2 = (const float*)d_in[1];
    const float* feat3 = (const float*)d_in[2];
    const float* W1    = (const float*)d_in[3];
    const float* W1s   = (const float*)d_in[4];
    const float* W2    = (const float*)d_in[5];
    const float* W2s   = (const float*)d_in[6];
    const float* W3    = (const float*)d_in[7];
    const float* W3p   = (const float*)d_in[8];
    const float* W3s   = (const float*)d_in[9];
    const float* W3t   = (const float*)d_in[10];
    const int* nbr1    = (const int*)d_in[11];
    const int* nbr2    = (const int*)d_in[12];
    const int* nbr3    = (const int*)d_in[13];
    const int* parent2 = (const int*)d_in[14];
    const int* parent3 = (const int*)d_in[15];
    const int* coords1 = (const int*)d_in[16];
    const int* coords2 = (const int*)d_in[17];

    const int N1 = in_sizes[0] / 80;
    const int N2 = in_sizes[1] / 48;
    const int N3 = in_sizes[2] / 16;

    float* out = (float*)d_out;
    float* o_points = out;                              // [N3,10]
    float* o_ppn1   = o_points + (size_t)N3 * 10;       // [N1,6]
    float* o_ppn2   = o_ppn1 + (size_t)N1 * 6;          // [N2,6]
    float* o_mask1  = o_ppn2 + (size_t)N2 * 6;          // [N1]
    float* o_mask2  = o_mask1 + (size_t)N1;             // [N2]

    char* wp = (char*)d_ws;
    auto alloc = [&](size_t bytes) -> char* {
        char* r = wp; wp += (bytes + 255) & ~(size_t)255; return r;
    };
    auto A256 = [](size_t b) { return (b + 255) & ~(size_t)255; };

    f16*   WT1 = (f16*)alloc((size_t)80 * 28 * 160 * 2);
    f16*   WT2 = (f16*)alloc((size_t)48 * 28 * 96 * 2);
    f16*   FG1 = (f16*)alloc((size_t)2 * 5 * 4 * 512 * 2);
    f16*   FG2 = (f16*)alloc((size_t)2 * 3 * 4 * 512 * 2);
    float* act3 = (float*)alloc((size_t)N3 * 4);
    int*   cnts = (int*)alloc(2 * 4);    // [cntz, cntp]

    // Fa: split features (levels 1,2 sequentially)
    size_t fa1 = (size_t)(N1 + 1) * 320, fa2 = (size_t)(N2 + 1) * 192;
    f16* Fa = (f16*)alloc(fa1 > fa2 ? fa1 : fa2);

    // P union: P projection (levels 1,2), then level-3 flags/lists/zbuf.
    // flagz/flagp adjacent -> single memset.
    size_t pmax = (size_t)(N1 > N2 ? N1 : N2) * 216 + 256;
    size_t l3b = 4 * A256((size_t)N3 * 4) + A256((size_t)N3 * 16 * 4);
    size_t szP = pmax > l3b ? pmax : l3b;
    char* Pu = alloc(szP);
    float* P = (float*)Pu;
    char* q3 = Pu;
    int*   flagz = (int*)q3; q3 += A256((size_t)N3 * 4);
    int*   flagp = (int*)q3; q3 += A256((size_t)N3 * 4);
    int*   listz = (int*)q3; q3 += A256((size_t)N3 * 4);
    int*   listp = (int*)q3; q3 += A256((size_t)N3 * 4);
    float* zbuf  = (float*)q3;

    auto cdiv = [](long long a, long long b) { return (int)((a + b - 1) / b); };

    hipMemsetAsync(cnts, 0, 2 * 4, stream);
    hipMemsetAsync(o_points, 0, (size_t)N3 * 10 * 4, stream);

    // ---- weight prep ----
    prep_wt<80><<<700, 256, 0, stream>>>(W1, WT1);
    prep_wt<48><<<cdiv(48 * 28 * 48, 256), 256, 0, stream>>>(W2, WT2);
    prep_gfrag<80><<<80, 256, 0, stream>>>(W1s, FG1);
    prep_gfrag<48><<<48, 256, 0, stream>>>(W2s, FG2);

    // ---- level 1: fused conv+P-projection -> fused finalize ----
    {
        int Tc = cdiv(N1, 64);
        dim3 gc(8 * cdiv(Tc, 8));
        split_gated<80><<<cdiv((size_t)(N1 + 1) * 80, 256), 256, 0, stream>>>(
            feat1, nullptr, nullptr, Fa, N1);
        conv_tile<80, false><<<gc, 256, 0, stream>>>(Fa, nbr1, WT1, FG1, P, N1, Tc);
        finalize_gather<<<2048, 256, 0, stream>>>(
            coords1, P, nbr1, o_ppn1, o_mask1, N1);
    }

    // ---- level 2: fused conv+P-projection -> fused finalize ----
    {
        int Tc = cdiv(N2, 64);
        dim3 gc(8 * cdiv(Tc, 8));
        split_gated<48><<<cdiv((size_t)(N2 + 1) * 48, 256), 256, 0, stream>>>(
            feat2, o_mask1, parent2, Fa, N2);
        conv_tile<48, true><<<gc, 256, 0, stream>>>(Fa, nbr2, WT2, FG2, P, N2, Tc);
        finalize_gather<<<2048, 256, 0, stream>>>(
            coords2, P, nbr2, o_ppn2, o_mask2, N2);
    }

    // ---- level 3: fused gate+expand -> compact -> z -> expand -> compact -> pts
    hipMemsetAsync(flagz, 0, 2 * A256((size_t)N3 * 4), stream);  // flagz+flagp
    gate_expand<<<cdiv(N3, 256), 256, 0, stream>>>(o_mask2, parent3, nbr3,
                                                   act3, flagz, N3);
    compact_kernel<<<cdiv(N3, 256), 256, 0, stream>>>(flagz, listz, &cnts[0], N3);
    lvl3_z_compute<<<2048, 256, 0, stream>>>(feat3, nbr3, act3, W3, zbuf,
                                             listz, &cnts[0], N3);
    expand_kernel<<<cdiv(N3, 256), 256, 0, stream>>>(flagz, nbr3, flagp, N3);
    compact_kernel<<<cdiv(N3, 256), 256, 0, stream>>>(flagp, listp, &cnts[1], N3);
    lvl3_pts_compute<<<2048, 256, 0, stream>>>(zbuf, flagz, nbr3, W3p, W3s, W3t,
                                               o_points, listp, &cnts[1], N3);
}